// Round 4
// baseline (87.262 us; speedup 1.0000x reference)
//
#include <hip/hip_runtime.h>
#include <cstdint>

// B=4, L=4096, D=3, VOCAB=8192
#define N_ROWS   16384
#define VOCAB    8192
#define BLOCK    512                   // 8 waves
#define NWAVES   (BLOCK / 64)          // 8
#define RPW      8                     // rows per wave (all in registers)
#define ROWS_PB  (NWAVES * RPW)        // 64 rows per block
#define GRID     (N_ROWS / ROWS_PB)    // 256 blocks = 1/CU
#define PIECE    1024                  // codes staged per piece (16 KiB)
#define NPIECE   (VOCAB / PIECE)       // 8

typedef unsigned long long u64;

// d_out layout (floats): [0,49152) quant_ste | [49152,65536) idx as float | [65536] vq_loss
// d_ws: [0, GRID*4) float block partials

// ---------------------------------------------------------------------------
// Fused kernel. Wave w owns 8 rows (x in regs, uniform across lanes); lane l
// scans codes p*1024 + j*64 + l. One ds_read_b128 feeds 8 row-evals (LDS
// instrs cut 8x vs R2 -- R2 was LDS-pipe-bound at ~41us).
// LDS stores (2*e0, 2*e1, 2*e2, ||e||^2): fma-chain on doubled e is bitwise
// equal to 2*xe (exact pow2 scaling), saving the fadd(xe,xe) per candidate.
// Distance rounding sequence otherwise frozen to the R1/R2-validated form.
// u64 key (dist_bits<<32 | code) gives exact np.argmin first-index ties.
// ---------------------------------------------------------------------------
__global__ __launch_bounds__(BLOCK, 2) void vq_main_kernel(
    const float* __restrict__ feats, const float* __restrict__ emb,
    float* __restrict__ out_quant, float* __restrict__ out_idx,
    float* __restrict__ partial)
{
    __shared__ float4 sE[PIECE];
    __shared__ float  wsum[NWAVES];

    const int tid   = threadIdx.x;
    const int lane  = tid & 63;
    const int wave  = tid >> 6;
    const int wrow0 = blockIdx.x * ROWS_PB + wave * RPW;

    // 8 rows' features in registers (lane-uniform broadcast loads)
    float x0[RPW], x1[RPW], x2[RPW], xx[RPW];
    #pragma unroll
    for (int r = 0; r < RPW; ++r) {
        x0[r] = feats[3 * (wrow0 + r) + 0];
        x1[r] = feats[3 * (wrow0 + r) + 1];
        x2[r] = feats[3 * (wrow0 + r) + 2];
        xx[r] = __fadd_rn(__fadd_rn(__fmul_rn(x0[r], x0[r]), __fmul_rn(x1[r], x1[r])),
                          __fmul_rn(x2[r], x2[r]));
    }

    // prefetch piece 0 (2 codes/thread: tid and tid+512)
    const float* g = emb + 3 * tid;
    float a0 = g[0],    a1 = g[1],    a2 = g[2];
    float b0 = g[1536], b1 = g[1537], b2 = g[1538];

    float best[RPW];
    int   bpj[RPW];   // best p*16+j per row (code = (bpj>>4)*1024 + (bpj&15)*64 + lane)
    #pragma unroll
    for (int r = 0; r < RPW; ++r) { best[r] = __int_as_float(0x7f800000); bpj[r] = 0; }

    for (int p = 0; p < NPIECE; ++p) {
        __syncthreads();   // previous piece fully consumed
        {
            const float eea = __fadd_rn(__fadd_rn(__fmul_rn(a0, a0), __fmul_rn(a1, a1)),
                                        __fmul_rn(a2, a2));
            const float eeb = __fadd_rn(__fadd_rn(__fmul_rn(b0, b0), __fmul_rn(b1, b1)),
                                        __fmul_rn(b2, b2));
            sE[tid]         = make_float4(a0 + a0, a1 + a1, a2 + a2, eea);
            sE[tid + BLOCK] = make_float4(b0 + b0, b1 + b1, b2 + b2, eeb);
        }
        __syncthreads();

        // issue next piece's global loads; hide under the 16x8 eval phase
        if (p + 1 < NPIECE) {
            const float* gn = emb + 3 * ((p + 1) * PIECE + tid);
            a0 = gn[0];    a1 = gn[1];    a2 = gn[2];
            b0 = gn[1536]; b1 = gn[1537]; b2 = gn[1538];
        }

        const int pj0 = p * 16;
        #pragma unroll
        for (int j = 0; j < 16; ++j) {
            const float4 E = sE[j * 64 + lane];   // 16B/lane, conflict-free
            const int pj = pj0 + j;
            #pragma unroll
            for (int r = 0; r < RPW; ++r) {
                const float xe2 = __fmaf_rn(x2[r], E.z,
                                  __fmaf_rn(x1[r], E.y, __fmul_rn(x0[r], E.x)));
                const float d = __fadd_rn(__fsub_rn(xx[r], xe2), E.w);
                if (d < best[r]) { best[r] = d; bpj[r] = pj; }   // strict <: first idx
            }
        }
    }

    // per-row cross-lane argmin (butterfly -> all lanes hold the min key)
    u64 key[RPW];
    #pragma unroll
    for (int r = 0; r < RPW; ++r) {
        const unsigned code = (unsigned)((bpj[r] >> 4) * PIECE + (bpj[r] & 15) * 64 + lane);
        u64 k = ((u64)__float_as_uint(best[r]) << 32) | code;
        #pragma unroll
        for (int off = 1; off < 64; off <<= 1) {
            const u64 o = __shfl_xor(k, off, 64);
            if (o < k) k = o;
        }
        key[r] = k;
    }

    // lane r < 8 emits row wrow0 + r (static select chain, no runtime indexing)
    u64 mykey = key[0];
    #pragma unroll
    for (int r = 1; r < RPW; ++r) mykey = (lane == r) ? key[r] : mykey;

    float s = 0.0f;
    if (lane < RPW) {
        const int row = wrow0 + lane;
        const unsigned idx = (unsigned)(mykey & 0xffffffffULL);
        const float e0 = emb[3 * idx + 0];
        const float e1 = emb[3 * idx + 1];
        const float e2 = emb[3 * idx + 2];
        const float fx0 = feats[3 * row + 0];
        const float fx1 = feats[3 * row + 1];
        const float fx2 = feats[3 * row + 2];
        out_quant[3 * row + 0] = __fadd_rn(fx0, __fsub_rn(e0, fx0));
        out_quant[3 * row + 1] = __fadd_rn(fx1, __fsub_rn(e1, fx1));
        out_quant[3 * row + 2] = __fadd_rn(fx2, __fsub_rn(e2, fx2));
        out_idx[row] = (float)idx;
        const float d0 = e0 - fx0, d1 = e1 - fx1, d2 = e2 - fx2;
        s = d0 * d0 + d1 * d1 + d2 * d2;
    }

    // block loss partial: wave butterfly (lanes >= 8 contribute 0) -> LDS -> tid 0
    #pragma unroll
    for (int off = 1; off < 64; off <<= 1) s += __shfl_xor(s, off, 64);
    if (lane == 0) wsum[wave] = s;
    __syncthreads();
    if (tid == 0) {
        float t = 0.0f;
        #pragma unroll
        for (int w = 0; w < NWAVES; ++w) t += wsum[w];
        partial[blockIdx.x] = t;
    }
}

// ---------------------------------------------------------------------------
// Reduce GRID block partials -> vq_loss = m + 0.25*m, m = mean(sq)
// ---------------------------------------------------------------------------
__global__ __launch_bounds__(GRID) void vq_loss_kernel(
    const float* __restrict__ partial, float* __restrict__ out_loss)
{
    __shared__ float wsum[GRID / 64];
    float s = partial[threadIdx.x];
    #pragma unroll
    for (int off = 1; off < 64; off <<= 1) s += __shfl_xor(s, off, 64);
    if ((threadIdx.x & 63) == 0) wsum[threadIdx.x >> 6] = s;
    __syncthreads();
    if (threadIdx.x == 0) {
        float t = 0.0f;
        #pragma unroll
        for (int w = 0; w < GRID / 64; ++w) t += wsum[w];
        const float m = t / (float)(N_ROWS * 3);
        out_loss[0] = __fadd_rn(m, __fmul_rn(0.25f, m));
    }
}

extern "C" void kernel_launch(void* const* d_in, const int* in_sizes, int n_in,
                              void* d_out, int out_size, void* d_ws, size_t ws_size,
                              hipStream_t stream)
{
    const float* feats = (const float*)d_in[0];   // [4,4096,3] f32
    const float* emb   = (const float*)d_in[1];   // [8192,3]   f32
    float* out = (float*)d_out;
    float* partial = (float*)d_ws;

    vq_main_kernel<<<GRID, BLOCK, 0, stream>>>(
        feats, emb, out, out + (size_t)N_ROWS * 3, partial);
    vq_loss_kernel<<<1, GRID, 0, stream>>>(partial, out + (size_t)N_ROWS * 4);
}